// Round 1
// baseline (312.145 us; speedup 1.0000x reference)
//
#include <hip/hip_runtime.h>
#include <hip/hip_bf16.h>

// 24-qubit brickwork circuit simulator.
// State: flat index i in [0, 2^24), wire w <-> bit (23-w).
// Gate g on wires (w,w+1): 4x4 matrix M[v][u] = G[u0,v0,u1,v1] applied to the
// 4 amplitudes selected by bits p0=23-w (value v0) and p1=22-w (value v1).
//
// 3-pass schedule (dependency-checked):
//  Pass1: tile = bits 0..13 (wires 10..23), init fused, 24 gates.
//  Pass2a: tile = bits 0..5 + bits 10..17, 8 gates (wires 6..12).
//  Pass2b: tile = bits 0..4 + bits 15..23, 14 gates (wires 0..8).

#define TILE_N 16384

__device__ __forceinline__ void stage_gate_matrices(
    float* gm, const float* __restrict__ gates, const int* glist, int ng, int tid) {
  for (int t = tid; t < ng * 16; t += 256) {
    int gate = t >> 4;
    int v = (t >> 2) & 3;   // output index (v0,v1)
    int u = t & 3;          // input index (u0,u1)
    // gates[g] axes (in0,out0,in1,out1): flat = in0*8 + out0*4 + in1*2 + out1
    gm[t] = gates[glist[gate] * 16 + (u >> 1) * 8 + (v >> 1) * 4 + (u & 1) * 2 + (v & 1)];
  }
}

__device__ __forceinline__ void apply_gates(
    float* tile, const float* gm, const int* q1l, int ng, int tid) {
  for (int gi = 0; gi < ng; ++gi) {
    const float* m = &gm[gi * 16];
    float m0 = m[0],  m1 = m[1],  m2 = m[2],  m3 = m[3];
    float m4 = m[4],  m5 = m[5],  m6 = m[6],  m7 = m[7];
    float m8 = m[8],  m9 = m[9],  m10 = m[10], m11 = m[11];
    float m12 = m[12], m13 = m[13], m14 = m[14], m15 = m[15];
    int q1 = q1l[gi];
    int s = 1 << q1;
#pragma unroll
    for (int t = 0; t < 16; ++t) {
      int k = tid + (t << 8);                 // group index, 4096 groups
      int low = k & (s - 1);
      int high = k >> q1;
      int base = (high << (q1 + 2)) | low;    // insert two zero bits at q1
      float a0 = tile[base];
      float a1 = tile[base + s];
      float a2 = tile[base + 2 * s];
      float a3 = tile[base + 3 * s];
      tile[base]         = m0 * a0 + m1 * a1 + m2 * a2 + m3 * a3;
      tile[base + s]     = m4 * a0 + m5 * a1 + m6 * a2 + m7 * a3;
      tile[base + 2 * s] = m8 * a0 + m9 * a1 + m10 * a2 + m11 * a3;
      tile[base + 3 * s] = m12 * a0 + m13 * a1 + m14 * a2 + m15 * a3;
    }
    __syncthreads();
  }
}

// ---------------- Pass 1: init + gates on wires 10..23 (bits 0..13) ----------
__global__ __launch_bounds__(256) void k_pass1(
    const float* __restrict__ states, const float* __restrict__ gates,
    float* __restrict__ out) {
  __shared__ float tile[TILE_N];
  __shared__ float gm[24 * 16];
  __shared__ float loT[128];
  __shared__ float hiT[128];
  static const int glist[24] = {5, 6, 7, 8, 9, 10, 11,      // L0 (10,11)..(22,23)
                                17, 18, 19, 20, 21, 22,     // L1 (11,12)..(21,22)
                                29, 30, 31, 32, 33, 34,     // L2 (12,13)..(22,23)
                                41, 42, 43, 44, 45};        // L3 (13,14)..(21,22)
  static const int q1l[24] = {12, 10, 8, 6, 4, 2, 0,
                              11, 9, 7, 5, 3, 1,
                              10, 8, 6, 4, 2, 0,
                              9, 7, 5, 3, 1};
  int tid = threadIdx.x;
  int b = blockIdx.x;  // global bits 14..23

  stage_gate_matrices(gm, gates, glist, 24, tid);

  // product tables: loT over bits 0..6 (wires 23..17), hiT over bits 7..13 (wires 16..10)
  if (tid < 128) {
    float p = 1.f;
    for (int k = 0; k < 7; ++k) p *= states[(23 - k) * 2 + ((tid >> k) & 1)];
    loT[tid] = p;
  } else {
    int y = tid - 128;
    float p = 1.f;
    for (int k = 0; k < 7; ++k) p *= states[(16 - k) * 2 + ((y >> k) & 1)];
    hiT[y] = p;
  }
  // block prefix over wires 0..9 (global bits 14..23; b bit k <-> wire 9-k)
  float pref = 1.f;
  for (int w = 0; w < 10; ++w) pref *= states[w * 2 + ((b >> (9 - w)) & 1)];
  __syncthreads();

#pragma unroll
  for (int e = 0; e < 64; ++e) {
    int j = tid + (e << 8);
    tile[j] = pref * hiT[j >> 7] * loT[j & 127];
  }
  __syncthreads();

  apply_gates(tile, gm, q1l, 24, tid);

  const long long obase = ((long long)b) << 14;
#pragma unroll
  for (int r = 0; r < 16; ++r) {
    int j = (tid + (r << 8)) << 2;
    *(float4*)(&out[obase + j]) = *(const float4*)(&tile[j]);
  }
}

// ---------------- Pass 2a: gates on wires 6..12 (global bits 11..17) ---------
__global__ __launch_bounds__(256) void k_pass2a(
    const float* __restrict__ gates, float* __restrict__ out) {
  __shared__ float tile[TILE_N];
  __shared__ float gm[8 * 16];
  static const int glist[8] = {3, 4,      // L0 (6,7),(8,9)
                               15, 16,    // L1 (7,8),(9,10)
                               27, 28,    // L2 (8,9),(10,11)
                               39, 40};   // L3 (9,10),(11,12)
  static const int q1l[8] = {12, 10, 11, 9, 10, 8, 9, 7};  // local = p1 - 4
  int tid = threadIdx.x;
  int b = blockIdx.x;
  int mid = b & 15;   // global bits 6..9
  int top = b >> 4;   // global bits 18..23
  stage_gate_matrices(gm, gates, glist, 8, tid);

  const long long gbase = (((long long)top) << 18) | ((long long)mid << 6);
#pragma unroll
  for (int r = 0; r < 16; ++r) {
    int j = (tid + (r << 8)) << 2;
    int h = j >> 6;       // global bits 10..17
    int l = j & 63;       // global bits 0..5
    *(float4*)(&tile[j]) = *(const float4*)(&out[gbase + (((long long)h) << 10) + l]);
  }
  __syncthreads();

  apply_gates(tile, gm, q1l, 8, tid);

#pragma unroll
  for (int r = 0; r < 16; ++r) {
    int j = (tid + (r << 8)) << 2;
    int h = j >> 6;
    int l = j & 63;
    *(float4*)(&out[gbase + (((long long)h) << 10) + l]) = *(const float4*)(&tile[j]);
  }
}

// ---------------- Pass 2b: gates on wires 0..8 (global bits 15..23) ----------
__global__ __launch_bounds__(256) void k_pass2b(
    const float* __restrict__ gates, float* __restrict__ out) {
  __shared__ float tile[TILE_N];
  __shared__ float gm[14 * 16];
  static const int glist[14] = {0, 1, 2,          // L0 (0,1),(2,3),(4,5)
                                12, 13, 14,       // L1 (1,2),(3,4),(5,6)
                                23, 24, 25, 26,   // L2 (0,1),(2,3),(4,5),(6,7)
                                35, 36, 37, 38};  // L3 (1,2),(3,4),(5,6),(7,8)
  static const int q1l[14] = {12, 10, 8,
                              11, 9, 7,
                              12, 10, 8, 6,
                              11, 9, 7, 5};       // local = p1 - 10
  int tid = threadIdx.x;
  int b = blockIdx.x;  // global bits 5..14
  stage_gate_matrices(gm, gates, glist, 14, tid);

  const long long gbase = ((long long)b) << 5;
#pragma unroll
  for (int r = 0; r < 16; ++r) {
    int j = (tid + (r << 8)) << 2;
    int h = j >> 5;       // global bits 15..23
    int l = j & 31;       // global bits 0..4
    *(float4*)(&tile[j]) = *(const float4*)(&out[gbase + (((long long)h) << 15) + l]);
  }
  __syncthreads();

  apply_gates(tile, gm, q1l, 14, tid);

#pragma unroll
  for (int r = 0; r < 16; ++r) {
    int j = (tid + (r << 8)) << 2;
    int h = j >> 5;
    int l = j & 31;
    *(float4*)(&out[gbase + (((long long)h) << 15) + l]) = *(const float4*)(&tile[j]);
  }
}

extern "C" void kernel_launch(void* const* d_in, const int* in_sizes, int n_in,
                              void* d_out, int out_size, void* d_ws, size_t ws_size,
                              hipStream_t stream) {
  const float* states = (const float*)d_in[0];  // (24, 2) f32
  const float* gates = (const float*)d_in[1];   // (46, 2,2,2,2) f32
  float* out = (float*)d_out;                   // 2^24 f32

  k_pass1<<<1024, 256, 0, stream>>>(states, gates, out);
  k_pass2a<<<1024, 256, 0, stream>>>(gates, out);
  k_pass2b<<<1024, 256, 0, stream>>>(gates, out);
}

// Round 2
// 201.169 us; speedup vs baseline: 1.5517x; 1.5517x over previous
//
#include <hip/hip_runtime.h>
#include <hip/hip_bf16.h>

// 24-qubit brickwork circuit, register-resident gate application.
// State: flat index i in [0, 2^24), wire w <-> bit (23-w).
// Gate on wires (w,w+1): p1 = 22-w (low bit), p0 = p1+1. 4x4 matrix
// M[v][u] = G[u0,v0,u1,v1], u = (u0<<1)|u1 where u0 = bit p0, u1 = bit p1.
//
// Each thread holds 64 amps (a 6-bit register window of the 14-bit tile
// index j). Gates inside the window are unrolled FMAs; window changes go
// through an XOR-swizzled LDS transpose (conflict-free for all patterns).

#define SWZ(j) ((j) ^ (((j) >> 6) & 15) ^ ((((j) >> 10) & 1) << 4))

template<int A>
__device__ __forceinline__ void gate_regs(float v[64], const float* __restrict__ g) {
  // gate acts on register bits (A, A+1); indices all compile-time constant
  float m[16];
#pragma unroll
  for (int vv = 0; vv < 4; ++vv)
#pragma unroll
    for (int uu = 0; uu < 4; ++uu)
      m[vv * 4 + uu] = g[(uu >> 1) * 8 + (vv >> 1) * 4 + (uu & 1) * 2 + (vv & 1)];
  constexpr int S = 1 << A;
#pragma unroll
  for (int hi = 0; hi < (1 << (4 - A)); ++hi)
#pragma unroll
    for (int lo = 0; lo < S; ++lo) {
      const int base = (hi << (A + 2)) | lo;
      const float a0 = v[base], a1 = v[base + S], a2 = v[base + 2 * S], a3 = v[base + 3 * S];
      v[base]         = m[0]  * a0 + m[1]  * a1 + m[2]  * a2 + m[3]  * a3;
      v[base + S]     = m[4]  * a0 + m[5]  * a1 + m[6]  * a2 + m[7]  * a3;
      v[base + 2 * S] = m[8]  * a0 + m[9]  * a1 + m[10] * a2 + m[11] * a3;
      v[base + 3 * S] = m[12] * a0 + m[13] * a1 + m[14] * a2 + m[15] * a3;
    }
}

// layout address formulas (j = 14-bit tile index, t = thread 0..255, r = reg 0..63)
#define J_B(t, r)  (((r) << 8) | (t))                                  // regs j8..13
#define J_M(t, r)  ((((t) >> 4) << 10) | ((r) << 4) | ((t) & 15))      // regs j4..9
#define J_A(t, r)  (((t) << 6) | (r))                                  // regs j0..5
#define J_W(t, r)  ((((t) >> 5) << 11) | ((r) << 5) | ((t) & 31))      // regs j5..10

#define TRANSITION(JW, JR)                                   \
  do {                                                       \
    _Pragma("unroll")                                        \
    for (int r = 0; r < 64; ++r) tile[SWZ(JW(t, r))] = v[r]; \
    __syncthreads();                                         \
    _Pragma("unroll")                                        \
    for (int r = 0; r < 64; ++r) v[r] = tile[SWZ(JR(t, r))]; \
    __syncthreads();                                         \
  } while (0)

// ---------------- Pass 1: init + 24 gates on bits 0..13 (wires 10..23) -------
__global__ __launch_bounds__(256) void k_pass1(
    const float* __restrict__ states, const float* __restrict__ gates,
    float* __restrict__ out) {
  __shared__ float tile[16384];
  __shared__ float sLo[256];
  __shared__ float sHi[64];
  const int t = threadIdx.x;
  const int b = blockIdx.x;  // global bits 14..23 (wires 9..0)

  {
    float p = 1.f;
    for (int k = 0; k < 8; ++k) p *= states[(23 - k) * 2 + ((t >> k) & 1)];
    sLo[t] = p;  // product over j bits 0..7 (wires 23..16)
    if (t < 64) {
      float q = 1.f;
      for (int k = 0; k < 6; ++k) q *= states[(15 - k) * 2 + ((t >> k) & 1)];
      sHi[t] = q;  // product over j bits 8..13 (wires 15..10)
    }
  }
  float pref = 1.f;
  for (int k = 0; k < 10; ++k) pref *= states[(9 - k) * 2 + ((b >> k) & 1)];
  __syncthreads();

  float v[64];
  const float plT = pref * sLo[t];
#pragma unroll
  for (int r = 0; r < 64; ++r) v[r] = plT * sHi[r];  // B layout: regs = j8..13

  // Phase B (window base 8): (L0,q12) (L0,10) (L0,8) (L1,11) (L1,9) (L2,10)
  gate_regs<4>(v, gates + 16 * 5);
  gate_regs<2>(v, gates + 16 * 6);
  gate_regs<0>(v, gates + 16 * 7);
  gate_regs<3>(v, gates + 16 * 17);
  gate_regs<1>(v, gates + 16 * 18);
  gate_regs<2>(v, gates + 16 * 29);

  TRANSITION(J_B, J_M);  // regs -> j4..9

  // Phase M (base 4): (L0,6) (L0,4) (L1,7) (L1,5) (L2,8) (L2,6)
  gate_regs<2>(v, gates + 16 * 8);
  gate_regs<0>(v, gates + 16 * 9);
  gate_regs<3>(v, gates + 16 * 19);
  gate_regs<1>(v, gates + 16 * 20);
  gate_regs<4>(v, gates + 16 * 30);
  gate_regs<2>(v, gates + 16 * 31);

  TRANSITION(J_M, J_A);  // regs -> j0..5

  // Phase A (base 0): (L0,2) (L0,0) (L1,3) (L1,1) (L2,4) (L2,2) (L2,0) (L3,3) (L3,1)
  gate_regs<2>(v, gates + 16 * 10);
  gate_regs<0>(v, gates + 16 * 11);
  gate_regs<3>(v, gates + 16 * 21);
  gate_regs<1>(v, gates + 16 * 22);
  gate_regs<4>(v, gates + 16 * 32);
  gate_regs<2>(v, gates + 16 * 33);
  gate_regs<0>(v, gates + 16 * 34);
  gate_regs<3>(v, gates + 16 * 44);
  gate_regs<1>(v, gates + 16 * 45);

  TRANSITION(J_A, J_W);  // regs -> j5..10

  // Phase W (base 5): (L3,9) (L3,7) (L3,5)
  gate_regs<4>(v, gates + 16 * 41);
  gate_regs<2>(v, gates + 16 * 42);
  gate_regs<0>(v, gates + 16 * 43);

  const long long ob = ((long long)b) << 14;
#pragma unroll
  for (int r = 0; r < 64; ++r) out[ob | J_W(t, r)] = v[r];  // 2x128B segs/inst
}

// ---------------- Pass 2a: 8 gates, tile = global bits {0..5} u {10..17} -----
// local j: bits 0..5 = global 0..5, bits 6..13 = global 10..17
__global__ __launch_bounds__(256) void k_pass2a(
    const float* __restrict__ gates, float* __restrict__ out) {
  __shared__ float tile[16384];
  const int t = threadIdx.x;
  const int b = blockIdx.x;
  const long long base0 = (((long long)(b >> 4)) << 18) | ((long long)(b & 15) << 6);

  float v[64];
  // load, B layout (regs = local j8..13 = global 12..17); lanes = global 0..5
#pragma unroll
  for (int r = 0; r < 64; ++r) {
    const int j = J_B(t, r);
    v[r] = out[base0 | (((long long)(j >> 6)) << 10) | (j & 63)];
  }
  // Phase B (base 8): g3(q12) g4(q10) g15(q11) g16(q9) g27(q10) g28(q8) g39(q9)
  gate_regs<4>(v, gates + 16 * 3);
  gate_regs<2>(v, gates + 16 * 4);
  gate_regs<3>(v, gates + 16 * 15);
  gate_regs<1>(v, gates + 16 * 16);
  gate_regs<2>(v, gates + 16 * 27);
  gate_regs<0>(v, gates + 16 * 28);
  gate_regs<1>(v, gates + 16 * 39);

  TRANSITION(J_B, J_W);  // regs -> local j5..10

  // Phase W (base 5): g40 (q7)
  gate_regs<2>(v, gates + 16 * 40);

#pragma unroll
  for (int r = 0; r < 64; ++r) {
    const int j = J_W(t, r);
    out[base0 | (((long long)(j >> 6)) << 10) | (j & 63)] = v[r];
  }
}

// ---------------- Pass 2b: 14 gates, tile = global bits {0..4} u {15..23} ----
// local j: bits 0..4 = global 0..4, bits 5..13 = global 15..23
__global__ __launch_bounds__(256) void k_pass2b(
    const float* __restrict__ gates, float* __restrict__ out) {
  __shared__ float tile[16384];
  const int t = threadIdx.x;
  const int b = blockIdx.x;  // global bits 5..14

  float v[64];
#pragma unroll
  for (int r = 0; r < 64; ++r) {
    const int j = J_B(t, r);
    v[r] = out[(((long long)(j >> 5)) << 15) | ((long long)b << 5) | (j & 31)];
  }
  // Phase B (base 8): g0(q12) g1(q10) g2(q8) g12(q11) g13(q9) g23(q12) g24(q10) g35(q11)
  gate_regs<4>(v, gates + 16 * 0);
  gate_regs<2>(v, gates + 16 * 1);
  gate_regs<0>(v, gates + 16 * 2);
  gate_regs<3>(v, gates + 16 * 12);
  gate_regs<1>(v, gates + 16 * 13);
  gate_regs<4>(v, gates + 16 * 23);
  gate_regs<2>(v, gates + 16 * 24);
  gate_regs<3>(v, gates + 16 * 35);

  TRANSITION(J_B, J_W);  // regs -> local j5..10

  // Phase W (base 5): g14(q7) g25(q8) g26(q6) g36(q9) g37(q7) g38(q5)
  gate_regs<2>(v, gates + 16 * 14);
  gate_regs<3>(v, gates + 16 * 25);
  gate_regs<1>(v, gates + 16 * 26);
  gate_regs<4>(v, gates + 16 * 36);
  gate_regs<2>(v, gates + 16 * 37);
  gate_regs<0>(v, gates + 16 * 38);

#pragma unroll
  for (int r = 0; r < 64; ++r) {
    const int j = J_W(t, r);
    out[(((long long)(j >> 5)) << 15) | ((long long)b << 5) | (j & 31)] = v[r];
  }
}

extern "C" void kernel_launch(void* const* d_in, const int* in_sizes, int n_in,
                              void* d_out, int out_size, void* d_ws, size_t ws_size,
                              hipStream_t stream) {
  const float* states = (const float*)d_in[0];  // (24, 2) f32
  const float* gates = (const float*)d_in[1];   // (46, 2,2,2,2) f32
  float* out = (float*)d_out;                   // 2^24 f32

  k_pass1<<<1024, 256, 0, stream>>>(states, gates, out);
  k_pass2a<<<1024, 256, 0, stream>>>(gates, out);
  k_pass2b<<<1024, 256, 0, stream>>>(gates, out);
}